// Round 8
// baseline (198.925 us; speedup 1.0000x reference)
//
#include <hip/hip_runtime.h>

// Problem constants (fixed by the reference file)
#define BATCH   8
#define C_OUT_N 96
#define NK      11
#define C_IN_N  1056      // C_OUT_N * NK
#define GRP     4
#define HOUT    56
#define WOUT    56
#define HIN     60
#define WIN     60
#define EP      2

#define CH_DW   (HIN * WIN)   // 3600 dwords per channel, contiguous
#define BUF_DW  4096          // 3600 + 496 pad: DMA tail lands here, never read
#define NBUF    3             // triple buffer for counted-vmcnt pipeline
#define ROWS_PW 7             // 8 waves x 7 rows = 56 output rows

// Address-space pointer types for global_load_lds
typedef const float __attribute__((address_space(1)))* gas1_t;
typedef float       __attribute__((address_space(3)))* las3_t;

// DMA one 3600-dword channel into LDS. Every wave issues EXACTLY 2
// global_load_lds (uniform vmcnt bookkeeping): issue0 covers float4
// [wid*64+lane] (max 511 < 900); issue1 covers [512+wid*64+lane], tail
// lanes clamp the per-lane GLOBAL src and land in the pad (dw 3840..4095).
__device__ __forceinline__ void stage_chan(const float* src, float* dst, int tid)
{
    const int wid  = tid >> 6;
    const int lane = tid & 63;
    __builtin_amdgcn_global_load_lds((gas1_t)(src + (wid * 64 + lane) * 4),
                                     (las3_t)(dst + wid * 256), 16, 0, 0);
    int f1 = 512 + wid * 64 + lane;
    if (f1 > 899) f1 = 899;                       // clamp src; dest -> pad
    __builtin_amdgcn_global_load_lds((gas1_t)(src + f1 * 4),
                                     (las3_t)(dst + 2048 + wid * 256), 16, 0, 0);
}

// One block per (b, co); 512 threads = 8 waves; TRIPLE-buffered channel
// tiles with counted-vmcnt barriers (T3/T4 pattern): at each k we wait
// vmcnt(2) -- retaining the newest stage (2 instrs/wave) in flight --
// then raw s_barrier. stage(k+2) is issued AFTER compute(k), so the
// buffer being overwritten ((k+2)%3) was last read by compute(k-1),
// which every wave finished before this iteration's barrier.
__global__ __launch_bounds__(512, 3) void addshift_kernel(
    const float* __restrict__ x,
    const float* __restrict__ w1,
    const float* __restrict__ w2,
    const float* __restrict__ w3,
    const int*   __restrict__ pad_hv,       // (C_IN, 8)
    const int*   __restrict__ idx_identit,  // (C_OUT, 4)
    float* __restrict__ out)                // [out_h | out_v | out_i]
{
    const int co  = blockIdx.x;
    const int b   = blockIdx.y;
    const int tid = threadIdx.x;

    __shared__ __align__(16) float buf[NBUF][BUF_DW];   // 49152 B -> 3 blocks/CU

    const int wave = tid >> 6;
    const int w    = tid & 63;
    const int wc   = (w < WOUT) ? w : (WOUT - 1);    // clamp idle lanes
    const int h0   = __builtin_amdgcn_readfirstlane(wave * ROWS_PW); // scalar
    const int cV   = wc + EP;                        // V/I column, always valid

    // Block-uniform identity-gather info
    int   kI[GRP];
    float w3v[GRP];
#pragma unroll
    for (int g = 0; g < GRP; ++g) {
        kI[g]  = idx_identit[co * GRP + g] - co * NK;   // in [0, NK)
        w3v[g] = w3[g * C_OUT_N + co];
    }

    float accH[ROWS_PW], accV[ROWS_PW], accI[ROWS_PW];
#pragma unroll
    for (int i = 0; i < ROWS_PW; ++i) { accH[i] = 0.f; accV[i] = 0.f; accI[i] = 0.f; }

    const float* chan_base = x + ((size_t)b * C_IN_N + (size_t)co * NK) * CH_DW;

    // Prologue: DMA channels 0 and 1.
    stage_chan(chan_base,                     buf[0], tid);
    stage_chan(chan_base + (size_t)CH_DW,     buf[1], tid);

#pragma unroll 1
    for (int k = 0; k < NK; ++k) {
        // Counted drain: keep newest stage (2 loads) in flight, drain older
        // -> stage(k) complete in THIS wave; barrier -> complete in ALL waves.
        if (k < NK - 1) { asm volatile("s_waitcnt vmcnt(2)" ::: "memory"); }
        else            { asm volatile("s_waitcnt vmcnt(0)" ::: "memory"); }
        __builtin_amdgcn_s_barrier();

        const float* __restrict__ bf = buf[k % NBUF];

        const int c = co * NK + k;
        int ph[GRP], pv[GRP];
        float a1[GRP], a2[GRP];
#pragma unroll
        for (int g = 0; g < GRP; ++g) {
            ph[g] = pad_hv[c * 8 + g];
            pv[g] = pad_hv[c * 8 + 4 + g];
            a1[g] = w1[g * C_IN_N + c];
            a2[g] = w2[g * C_IN_N + c];
        }
        float wi = 0.f;
#pragma unroll
        for (int g = 0; g < GRP; ++g)
            if (kI[g] == k) wi += w3v[g];

        // ---- H pass: rows h0+i+EP always valid; col clamped + weight-masked.
        // Split rows 0-3 / 4-6 about a rebased pointer so every dword offset
        // is <= 255 -> guaranteed ds_read2_b32 pairing (4 LDS instrs/group).
        const float* hrow = bf + (h0 + EP) * WIN;
#pragma unroll
        for (int g = 0; g < GRP; ++g) {
            int ix   = wc + EP + ph[g];                       // may be OOB
            float wh = ((unsigned)ix < (unsigned)WIN) ? a1[g] : 0.f;
            int ixc  = ix < 0 ? 0 : (ix > WIN - 1 ? WIN - 1 : ix);
            const float* p = hrow + ixc;
            const float* q = p + 4 * WIN;                     // rows 4..6
#pragma unroll
            for (int i = 0; i < 4; ++i)
                accH[i] = fmaf(p[i * WIN], wh, accH[i]);
#pragma unroll
            for (int i = 0; i < 3; ++i)
                accH[4 + i] = fmaf(q[i * WIN], wh, accH[4 + i]);
        }

        // ---- V pass: col cV valid; rows rb..rb+6, wave-uniform fast/slow.
#pragma unroll
        for (int g = 0; g < GRP; ++g) {
            const int rb = h0 + EP + pv[g];                   // scalar
            if (rb >= 0 && rb <= HIN - ROWS_PW) {             // fast: all rows in
                const float* p = bf + rb * WIN + cV;
                const float* q = p + 4 * WIN;
#pragma unroll
                for (int i = 0; i < 4; ++i)
                    accV[i] = fmaf(p[i * WIN], a2[g], accV[i]);
#pragma unroll
                for (int i = 0; i < 3; ++i)
                    accV[4 + i] = fmaf(q[i * WIN], a2[g], accV[4 + i]);
            } else {                                          // edge waves only
#pragma unroll
                for (int i = 0; i < ROWS_PW; ++i) {
                    int r    = rb + i;
                    float wv = ((unsigned)r < (unsigned)HIN) ? a2[g] : 0.f;
                    int rc   = r < 0 ? 0 : (r > HIN - 1 ? HIN - 1 : r);
                    accV[i]  = fmaf(bf[rc * WIN + cV], wv, accV[i]);
                }
            }
        }

        // ---- Identity pass (block-uniform branch)
        if (wi != 0.f) {
            const float* p = bf + (h0 + EP) * WIN + cV;
            const float* q = p + 4 * WIN;
#pragma unroll
            for (int i = 0; i < 4; ++i)
                accI[i] = fmaf(p[i * WIN], wi, accI[i]);
#pragma unroll
            for (int i = 0; i < 3; ++i)
                accI[4 + i] = fmaf(q[i * WIN], wi, accI[4 + i]);
        }

        // ---- Issue stage(k+2) AFTER compute(k): its target buffer was last
        // read by compute(k-1), finished in all waves before this barrier.
        if (k + 2 < NK)
            stage_chan(chan_base + (size_t)(k + 2) * CH_DW, buf[(k + 2) % NBUF], tid);
    }

    // Epilogue: per-lane row stores (slab-store A/B in r2 showed no diff).
    if (w < WOUT) {
        const size_t OSZ  = (size_t)BATCH * C_OUT_N * HOUT * WOUT;
        const size_t base = (((size_t)b * C_OUT_N + co) * HOUT + h0) * WOUT + w;
#pragma unroll
        for (int i = 0; i < ROWS_PW; ++i) {
            out[base + (size_t)i * WOUT]           = accH[i];
            out[OSZ + base + (size_t)i * WOUT]     = accV[i];
            out[2 * OSZ + base + (size_t)i * WOUT] = accI[i];
        }
    }
}

extern "C" void kernel_launch(void* const* d_in, const int* in_sizes, int n_in,
                              void* d_out, int out_size, void* d_ws, size_t ws_size,
                              hipStream_t stream) {
    const float* x   = (const float*)d_in[0];
    const float* w1  = (const float*)d_in[1];
    const float* w2  = (const float*)d_in[2];
    const float* w3  = (const float*)d_in[3];
    const int* pad_hv      = (const int*)d_in[4];
    const int* idx_identit = (const int*)d_in[5];
    float* out = (float*)d_out;

    dim3 grid(C_OUT_N, BATCH);   // 768 blocks, 512 threads
    dim3 block(512);
    addshift_kernel<<<grid, block, 0, stream>>>(x, w1, w2, w3, pad_hv, idx_identit, out);
}